// Round 3
// baseline (5517.788 us; speedup 1.0000x reference)
//
#include <hip/hip_runtime.h>
#include <math.h>

// EuclideanCodebook: N=131072 rows x d=128 fp32, K=1024 codes.
// bf16x3 split-precision MFMA (xh*eh + xl*eh + xh*el), per-row top-2 gap
// tracking, exact fp32 recheck of rows with gap < TAU.
// R2 post-mortem: 64 rows/wave spilled A-frags -> 1.07 GB scratch re-reads.
// R3: 32 rows/wave (~140 VGPRs, no spill), grid 1024 blocks.

typedef __attribute__((ext_vector_type(8)))  short short8_t;   // 8 bf16
typedef __attribute__((ext_vector_type(16))) float floatx16;   // 32x32 C frag

constexpr int D        = 128;
constexpr int KCODES   = 1024;
constexpr int NTILES   = 32;     // 1024 / 32 codes-per-tile
constexpr int ROWS_BLK = 128;    // 4 waves x 32 rows
constexpr float TAU    = 0.015f; // recheck margin >> max score error (~2e-3)

// ws layout (bytes)
constexpr size_t WS_COUNTER = 0;                    // uint flagged-row count
constexpr size_t WS_CSQ     = 256;                  // 1024 f32 ||e||^2
constexpr size_t WS_EHI     = 8192;                 // 1024*128 ushort, swizzled
constexpr size_t WS_ELO     = WS_EHI + 262144;
constexpr size_t WS_LIST    = WS_ELO + 262144;      // uint row ids (cap 131072)

#define GLOBAL_AS __attribute__((address_space(1)))
#define LDS_AS    __attribute__((address_space(3)))

__device__ inline unsigned short bf16_rne(float v, float* back) {
    unsigned u = __float_as_uint(v);
    unsigned r = (u + 0x7FFFu + ((u >> 16) & 1u)) >> 16;
    *back = __uint_as_float(r << 16);
    return (unsigned short)r;
}

// ---------------- prep: csq + swizzled bf16 hi/lo codebook ----------------
__global__ void ecb_prep(const float* __restrict__ embed, float* __restrict__ csq,
                         unsigned short* __restrict__ ehi, unsigned short* __restrict__ elo,
                         unsigned int* __restrict__ counter) {
    int n = blockIdx.x * 64 + threadIdx.x;
    if (n == 0) *counter = 0u;
    if (n >= KCODES) return;
    const int t = n >> 5, nn = n & 31, nm = nn & 15;
    const float* row = embed + (size_t)n * D;
    const size_t tb = (size_t)t * 32 * D + (size_t)nn * D;
    float s = 0.f;
    for (int cc = 0; cc < 16; ++cc) {
        float4 a  = *(const float4*)(row + cc * 8);
        float4 bq = *(const float4*)(row + cc * 8 + 4);
        s = fmaf(a.x, a.x, s);  s = fmaf(a.y, a.y, s);
        s = fmaf(a.z, a.z, s);  s = fmaf(a.w, a.w, s);
        s = fmaf(bq.x, bq.x, s); s = fmaf(bq.y, bq.y, s);
        s = fmaf(bq.z, bq.z, s); s = fmaf(bq.w, bq.w, s);
        float vv[8] = {a.x, a.y, a.z, a.w, bq.x, bq.y, bq.z, bq.w};
        unsigned short h[8], l[8];
#pragma unroll
        for (int j = 0; j < 8; ++j) {
            float hb, db;
            h[j] = bf16_rne(vv[j], &hb);
            l[j] = bf16_rne(vv[j] - hb, &db);
        }
        uint4 ph, pl;
        ph.x = (unsigned)h[0] | ((unsigned)h[1] << 16);
        ph.y = (unsigned)h[2] | ((unsigned)h[3] << 16);
        ph.z = (unsigned)h[4] | ((unsigned)h[5] << 16);
        ph.w = (unsigned)h[6] | ((unsigned)h[7] << 16);
        pl.x = (unsigned)l[0] | ((unsigned)l[1] << 16);
        pl.y = (unsigned)l[2] | ((unsigned)l[3] << 16);
        pl.z = (unsigned)l[4] | ((unsigned)l[5] << 16);
        pl.w = (unsigned)l[6] | ((unsigned)l[7] << 16);
        // XOR swizzle on the 16B chunk index -> conflict-free ds_read_b128 later
        size_t dst = tb + (size_t)((cc ^ nm) * 8);
        *(uint4*)(ehi + dst) = ph;
        *(uint4*)(elo + dst) = pl;
    }
    csq[n] = s;
}

// ---------------- main: MFMA scores + stuffed-index argmax ----------------
__global__ __launch_bounds__(256, 2)
void ecb_main(const float* __restrict__ x,
              const unsigned short* __restrict__ ehi, const unsigned short* __restrict__ elo,
              const float* __restrict__ csq, const float* __restrict__ embed,
              float* __restrict__ out_idx, float* __restrict__ out_q,
              unsigned int* __restrict__ counter, unsigned int* __restrict__ list) {
    __shared__ unsigned short ebuf[2][2][4096];   // [dbuf][hi/lo][32 codes x 128], 32 KB
    __shared__ float scsq[KCODES];                // 4 KB
    __shared__ int   sidx[ROWS_BLK];              // 512 B

    const int tid  = threadIdx.x;
    const int lane = tid & 63, wave = tid >> 6;
    const int col  = lane & 31, h = lane >> 5, colm = col & 15;
    const long rowblk = (long)blockIdx.x * ROWS_BLK;
    const int  roww   = wave * 32;

    for (int i = tid; i < KCODES; i += 256) scsq[i] = csq[i];

    // A prologue: 32 rows/wave of x -> bf16 hi/lo fragments in registers.
    // A[m][k]: m = lane&31, k = 8*(lane>>5) + j within each 16-chunk c.
    short8_t ah[8], al[8];
    {
        const float* xr = x + (rowblk + roww + col) * (long)D + h * 8;
#pragma unroll
        for (int c = 0; c < 8; ++c) {
            float4 a  = *(const float4*)(xr + c * 16);
            float4 bq = *(const float4*)(xr + c * 16 + 4);
            float vv[8] = {a.x, a.y, a.z, a.w, bq.x, bq.y, bq.z, bq.w};
            short8_t fh, fl;
#pragma unroll
            for (int j = 0; j < 8; ++j) {
                float hb, db;
                fh[j] = (short)bf16_rne(vv[j], &hb);
                fl[j] = (short)bf16_rne(vv[j] - hb, &db);
            }
            ah[c] = fh;
            al[c] = fl;
        }
    }

    auto stage = [&](int t, int b) {
        // 8KB hi + 8KB lo per tile; per wave: 2x 1KB issues each.
        const char* gh = (const char*)(ehi) + (size_t)t * 8192;
        const char* gl = (const char*)(elo) + (size_t)t * 8192;
        char* lh = (char*)&ebuf[b][0][0];
        char* ll = (char*)&ebuf[b][1][0];
#pragma unroll
        for (int i = 0; i < 2; ++i) {
            int off = i * 4096 + wave * 1024;
            __builtin_amdgcn_global_load_lds((const GLOBAL_AS unsigned int*)(gh + off + lane * 16),
                                             (LDS_AS unsigned int*)(lh + off), 16, 0, 0);
            __builtin_amdgcn_global_load_lds((const GLOBAL_AS unsigned int*)(gl + off + lane * 16),
                                             (LDS_AS unsigned int*)(ll + off), 16, 0, 0);
        }
    };

    float v1[16], v2[16];
#pragma unroll
    for (int j = 0; j < 16; ++j) { v1[j] = -INFINITY; v2[j] = -INFINITY; }

    stage(0, 0);
    __syncthreads();

    for (int t = 0; t < NTILES; ++t) {
        const int b = t & 1;
        if (t + 1 < NTILES) stage(t + 1, (t + 1) & 1);

        floatx16 acc;
#pragma unroll
        for (int i = 0; i < 16; ++i) acc[i] = 0.f;

#pragma unroll 2
        for (int s = 0; s < 8; ++s) {
            const int cc = 2 * s + h;
            const int idx = (col * 16 + (cc ^ colm)) * 8;   // elements
            short8_t bh = *(const short8_t*)&ebuf[b][0][idx];
            short8_t bl = *(const short8_t*)&ebuf[b][1][idx];
            acc = __builtin_amdgcn_mfma_f32_32x32x16_bf16(ah[s], bh, acc, 0, 0, 0);
            acc = __builtin_amdgcn_mfma_f32_32x32x16_bf16(al[s], bh, acc, 0, 0, 0);
            acc = __builtin_amdgcn_mfma_f32_32x32x16_bf16(ah[s], bl, acc, 0, 0, 0);
        }

        // epilogue: score = 2*dot - ||e||^2 ; stuff tile id (5b) into mantissa LSBs
        const float cs = scsq[t * 32 + col];
#pragma unroll
        for (int j = 0; j < 16; ++j) {
            float sc = fmaf(2.f, acc[j], -cs);
            unsigned u = (__float_as_uint(sc) & ~31u) | (unsigned)t;
            float cand = __uint_as_float(u);
            float mn = fminf(v1[j], cand);
            v1[j] = fmaxf(v1[j], cand);
            v2[j] = fmaxf(v2[j], mn);
        }
        __syncthreads();
    }

    // cross-lane top-2 merge over the 32 columns of each half
#pragma unroll
    for (int j = 0; j < 16; ++j) {
        float a1 = v1[j], a2 = v2[j];
        int   c1 = ((__float_as_uint(a1) & 31u) << 5) | col;   // tile*32 + col
#pragma unroll
        for (int m = 1; m < 32; m <<= 1) {
            float o1 = __shfl_xor(a1, m, 64);
            int   oc = __shfl_xor(c1, m, 64);
            float o2 = __shfl_xor(a2, m, 64);
            float lo = fminf(a1, o1);
            if (o1 > a1) { a1 = o1; c1 = oc; }
            a2 = fmaxf(fmaxf(a2, o2), lo);
        }
        if (col == j) {
            int row_local = roww + (j & 3) + 8 * (j >> 2) + 4 * h;
            long grow = rowblk + row_local;
            sidx[row_local] = c1;
            out_idx[grow] = (float)c1;
            if (a1 - a2 < TAU) {
                unsigned p = atomicAdd(counter, 1u);
                list[p] = (unsigned)grow;
            }
        }
    }
    __syncthreads();

    // gather quantize = embed[best] (exact fp32 values, L2-hot)
    for (int i = tid; i < ROWS_BLK * 32; i += 256) {
        int r = i >> 5, q = i & 31;
        int code = sidx[r];
        float4 v = *(const float4*)(embed + (size_t)code * D + q * 4);
        *(float4*)(out_q + (rowblk + r) * (long)D + q * 4) = v;
    }
}

// ---------------- recheck: exact fp32 rescore of flagged rows ----------------
__global__ __launch_bounds__(256)
void ecb_recheck(const float* __restrict__ x, const float* __restrict__ embed,
                 const float* __restrict__ csq,
                 float* __restrict__ out_idx, float* __restrict__ out_q,
                 const unsigned int* __restrict__ counter,
                 const unsigned int* __restrict__ list, int N) {
    __shared__ float xs[D];
    __shared__ float bv[256];
    __shared__ int   bi[256];
    const int tid = threadIdx.x;
    unsigned cnt = *counter;
    if (cnt > (unsigned)N) cnt = (unsigned)N;

    for (unsigned it = blockIdx.x; it < cnt; it += gridDim.x) {
        const long row = (long)list[it];
        if (tid < 32) *(float4*)&xs[tid * 4] = *(const float4*)(x + row * D + tid * 4);
        __syncthreads();

        float best = -INFINITY; int bidx = 0;
#pragma unroll
        for (int g = 0; g < 4; ++g) {
            int code = tid + g * 256;
            const float* er = embed + (size_t)code * D;
            float dot = 0.f;
#pragma unroll
            for (int k = 0; k < 32; ++k) {
                float4 e = *(const float4*)(er + k * 4);
                dot = fmaf(xs[k * 4 + 0], e.x, dot);
                dot = fmaf(xs[k * 4 + 1], e.y, dot);
                dot = fmaf(xs[k * 4 + 2], e.z, dot);
                dot = fmaf(xs[k * 4 + 3], e.w, dot);
            }
            float sc = fmaf(2.f, dot, -csq[code]);
            if (sc > best || (sc == best && code < bidx)) { best = sc; bidx = code; }
        }
        bv[tid] = best; bi[tid] = bidx;
        __syncthreads();
        for (int s = 128; s > 0; s >>= 1) {
            if (tid < s) {
                float ov = bv[tid + s]; int oi = bi[tid + s];
                if (ov > bv[tid] || (ov == bv[tid] && oi < bi[tid])) { bv[tid] = ov; bi[tid] = oi; }
            }
            __syncthreads();
        }
        const int win = bi[0];
        if (tid == 0) out_idx[row] = (float)win;
        if (tid < 32) {
            float4 v = *(const float4*)(embed + (size_t)win * D + tid * 4);
            *(float4*)(out_q + row * D + tid * 4) = v;
        }
        __syncthreads();
    }
}

extern "C" void kernel_launch(void* const* d_in, const int* in_sizes, int n_in,
                              void* d_out, int out_size, void* d_ws, size_t ws_size,
                              hipStream_t stream) {
    const float* x     = (const float*)d_in[0];
    const float* embed = (const float*)d_in[1];
    const int N = in_sizes[0] / D;   // 131072
    char* ws = (char*)d_ws;
    unsigned int*   counter = (unsigned int*)(ws + WS_COUNTER);
    float*          csq     = (float*)(ws + WS_CSQ);
    unsigned short* ehi     = (unsigned short*)(ws + WS_EHI);
    unsigned short* elo     = (unsigned short*)(ws + WS_ELO);
    unsigned int*   list    = (unsigned int*)(ws + WS_LIST);
    float* out_idx = (float*)d_out;
    float* out_q   = out_idx + N;

    hipLaunchKernelGGL(ecb_prep, dim3(16), dim3(64), 0, stream, embed, csq, ehi, elo, counter);
    hipLaunchKernelGGL(ecb_main, dim3(N / ROWS_BLK), dim3(256), 0, stream,
                       x, ehi, elo, csq, embed, out_idx, out_q, counter, list);
    hipLaunchKernelGGL(ecb_recheck, dim3(512), dim3(256), 0, stream,
                       x, embed, csq, out_idx, out_q, counter, list, N);
}

// Round 4
// 249.825 us; speedup vs baseline: 22.0867x; 22.0867x over previous
//
#include <hip/hip_runtime.h>
#include <math.h>

// EuclideanCodebook: N=131072 rows x d=128 fp32, K=1024 codes.
// bf16x3 split-precision MFMA (xh*eh + xl*eh + xh*el), per-row top-2 gap
// tracking, exact fp32 recheck of rows with gap < TAU.
// R2 post-mortem: 64 rows/wave -> A-frags spilled -> 1.07 GB scratch traffic.
// R3 post-mortem: "#pragma unroll 2" left s dynamic -> ah[s]/al[s] became
//   dynamically-indexed register arrays -> v_cndmask waterfall per MFMA
//   operand -> 4.5 ms of VALU. Fix: FULL unroll of s-loop (constant indices),
//   t-loop pinned at unroll 1 for code size.

typedef __attribute__((ext_vector_type(8)))  short short8_t;   // 8 bf16
typedef __attribute__((ext_vector_type(16))) float floatx16;   // 32x32 C frag

constexpr int D        = 128;
constexpr int KCODES   = 1024;
constexpr int NTILES   = 32;     // 1024 / 32 codes-per-tile
constexpr int ROWS_BLK = 128;    // 4 waves x 32 rows
constexpr float TAU    = 0.015f; // recheck margin >> max score error (~2e-3)

// ws layout (bytes)
constexpr size_t WS_COUNTER = 0;                    // uint flagged-row count
constexpr size_t WS_CSQ     = 256;                  // 1024 f32 ||e||^2
constexpr size_t WS_EHI     = 8192;                 // 1024*128 ushort, swizzled
constexpr size_t WS_ELO     = WS_EHI + 262144;
constexpr size_t WS_LIST    = WS_ELO + 262144;      // uint row ids (cap 131072)

#define GLOBAL_AS __attribute__((address_space(1)))
#define LDS_AS    __attribute__((address_space(3)))

__device__ inline unsigned short bf16_rne(float v, float* back) {
    unsigned u = __float_as_uint(v);
    unsigned r = (u + 0x7FFFu + ((u >> 16) & 1u)) >> 16;
    *back = __uint_as_float(r << 16);
    return (unsigned short)r;
}

// ---------------- prep: csq + swizzled bf16 hi/lo codebook ----------------
__global__ void ecb_prep(const float* __restrict__ embed, float* __restrict__ csq,
                         unsigned short* __restrict__ ehi, unsigned short* __restrict__ elo,
                         unsigned int* __restrict__ counter) {
    int n = blockIdx.x * 64 + threadIdx.x;
    if (n == 0) *counter = 0u;
    if (n >= KCODES) return;
    const int t = n >> 5, nn = n & 31, nm = nn & 15;
    const float* row = embed + (size_t)n * D;
    const size_t tb = (size_t)t * 32 * D + (size_t)nn * D;
    float s = 0.f;
#pragma unroll
    for (int cc = 0; cc < 16; ++cc) {
        float4 a  = *(const float4*)(row + cc * 8);
        float4 bq = *(const float4*)(row + cc * 8 + 4);
        s = fmaf(a.x, a.x, s);  s = fmaf(a.y, a.y, s);
        s = fmaf(a.z, a.z, s);  s = fmaf(a.w, a.w, s);
        s = fmaf(bq.x, bq.x, s); s = fmaf(bq.y, bq.y, s);
        s = fmaf(bq.z, bq.z, s); s = fmaf(bq.w, bq.w, s);
        float vv[8] = {a.x, a.y, a.z, a.w, bq.x, bq.y, bq.z, bq.w};
        unsigned short h[8], l[8];
#pragma unroll
        for (int j = 0; j < 8; ++j) {
            float hb, db;
            h[j] = bf16_rne(vv[j], &hb);
            l[j] = bf16_rne(vv[j] - hb, &db);
        }
        uint4 ph, pl;
        ph.x = (unsigned)h[0] | ((unsigned)h[1] << 16);
        ph.y = (unsigned)h[2] | ((unsigned)h[3] << 16);
        ph.z = (unsigned)h[4] | ((unsigned)h[5] << 16);
        ph.w = (unsigned)h[6] | ((unsigned)h[7] << 16);
        pl.x = (unsigned)l[0] | ((unsigned)l[1] << 16);
        pl.y = (unsigned)l[2] | ((unsigned)l[3] << 16);
        pl.z = (unsigned)l[4] | ((unsigned)l[5] << 16);
        pl.w = (unsigned)l[6] | ((unsigned)l[7] << 16);
        // XOR swizzle on the 16B chunk index -> conflict-free ds_read_b128 later
        size_t dst = tb + (size_t)((cc ^ nm) * 8);
        *(uint4*)(ehi + dst) = ph;
        *(uint4*)(elo + dst) = pl;
    }
    csq[n] = s;
}

// ---------------- main: MFMA scores + stuffed-index argmax ----------------
__global__ __launch_bounds__(256, 2)
void ecb_main(const float* __restrict__ x,
              const unsigned short* __restrict__ ehi, const unsigned short* __restrict__ elo,
              const float* __restrict__ csq, const float* __restrict__ embed,
              float* __restrict__ out_idx, float* __restrict__ out_q,
              unsigned int* __restrict__ counter, unsigned int* __restrict__ list) {
    __shared__ unsigned short ebuf[2][2][4096];   // [dbuf][hi/lo][32 codes x 128], 32 KB
    __shared__ float scsq[KCODES];                // 4 KB
    __shared__ int   sidx[ROWS_BLK];              // 512 B

    const int tid  = threadIdx.x;
    const int lane = tid & 63, wave = tid >> 6;
    const int col  = lane & 31, h = lane >> 5, colm = col & 15;
    const long rowblk = (long)blockIdx.x * ROWS_BLK;
    const int  roww   = wave * 32;

    for (int i = tid; i < KCODES; i += 256) scsq[i] = csq[i];

    // A prologue: 32 rows/wave of x -> bf16 hi/lo fragments in registers.
    // A[m][k]: m = lane&31, k = 8*(lane>>5) + j within each 16-chunk c.
    short8_t ah[8], al[8];
    {
        const float* xr = x + (rowblk + roww + col) * (long)D + h * 8;
#pragma unroll
        for (int c = 0; c < 8; ++c) {
            float4 a  = *(const float4*)(xr + c * 16);
            float4 bq = *(const float4*)(xr + c * 16 + 4);
            float vv[8] = {a.x, a.y, a.z, a.w, bq.x, bq.y, bq.z, bq.w};
            short8_t fh, fl;
#pragma unroll
            for (int j = 0; j < 8; ++j) {
                float hb, db;
                fh[j] = (short)bf16_rne(vv[j], &hb);
                fl[j] = (short)bf16_rne(vv[j] - hb, &db);
            }
            ah[c] = fh;
            al[c] = fl;
        }
    }

    auto stage = [&](int t, int b) {
        // 8KB hi + 8KB lo per tile; per wave: 2x 1KB issues each.
        const char* gh = (const char*)(ehi) + (size_t)t * 8192;
        const char* gl = (const char*)(elo) + (size_t)t * 8192;
        char* lh = (char*)&ebuf[b][0][0];
        char* ll = (char*)&ebuf[b][1][0];
#pragma unroll
        for (int i = 0; i < 2; ++i) {
            int off = i * 4096 + wave * 1024;
            __builtin_amdgcn_global_load_lds((const GLOBAL_AS unsigned int*)(gh + off + lane * 16),
                                             (LDS_AS unsigned int*)(lh + off), 16, 0, 0);
            __builtin_amdgcn_global_load_lds((const GLOBAL_AS unsigned int*)(gl + off + lane * 16),
                                             (LDS_AS unsigned int*)(ll + off), 16, 0, 0);
        }
    };

    float v1[16], v2[16];
#pragma unroll
    for (int j = 0; j < 16; ++j) { v1[j] = -INFINITY; v2[j] = -INFINITY; }

    stage(0, 0);
    __syncthreads();

#pragma unroll 1
    for (int t = 0; t < NTILES; ++t) {
        const int b = t & 1;
        if (t + 1 < NTILES) stage(t + 1, (t + 1) & 1);

        floatx16 acc;
#pragma unroll
        for (int i = 0; i < 16; ++i) acc[i] = 0.f;

        // FULL unroll: s must be a compile-time constant so ah[s]/al[s]
        // stay register-indexed (dynamic s -> v_cndmask waterfall, R3 bug).
#pragma unroll
        for (int s = 0; s < 8; ++s) {
            const int cc = 2 * s + h;
            const int idx = (col * 16 + (cc ^ colm)) * 8;   // elements
            short8_t bh = *(const short8_t*)&ebuf[b][0][idx];
            short8_t bl = *(const short8_t*)&ebuf[b][1][idx];
            acc = __builtin_amdgcn_mfma_f32_32x32x16_bf16(ah[s], bh, acc, 0, 0, 0);
            acc = __builtin_amdgcn_mfma_f32_32x32x16_bf16(al[s], bh, acc, 0, 0, 0);
            acc = __builtin_amdgcn_mfma_f32_32x32x16_bf16(ah[s], bl, acc, 0, 0, 0);
        }

        // epilogue: score = 2*dot - ||e||^2 ; stuff tile id (5b) into mantissa LSBs
        const float cs = scsq[t * 32 + col];
#pragma unroll
        for (int j = 0; j < 16; ++j) {
            float sc = fmaf(2.f, acc[j], -cs);
            unsigned u = (__float_as_uint(sc) & ~31u) | (unsigned)t;
            float cand = __uint_as_float(u);
            float mn = fminf(v1[j], cand);
            v1[j] = fmaxf(v1[j], cand);
            v2[j] = fmaxf(v2[j], mn);
        }
        __syncthreads();
    }

    // cross-lane top-2 merge over the 32 columns of each half
#pragma unroll
    for (int j = 0; j < 16; ++j) {
        float a1 = v1[j], a2 = v2[j];
        int   c1 = ((__float_as_uint(a1) & 31u) << 5) | col;   // tile*32 + col
#pragma unroll
        for (int m = 1; m < 32; m <<= 1) {
            float o1 = __shfl_xor(a1, m, 64);
            int   oc = __shfl_xor(c1, m, 64);
            float o2 = __shfl_xor(a2, m, 64);
            float lo = fminf(a1, o1);
            if (o1 > a1) { a1 = o1; c1 = oc; }
            a2 = fmaxf(fmaxf(a2, o2), lo);
        }
        if (col == j) {
            int row_local = roww + (j & 3) + 8 * (j >> 2) + 4 * h;
            long grow = rowblk + row_local;
            sidx[row_local] = c1;
            out_idx[grow] = (float)c1;
            if (a1 - a2 < TAU) {
                unsigned p = atomicAdd(counter, 1u);
                list[p] = (unsigned)grow;
            }
        }
    }
    __syncthreads();

    // gather quantize = embed[best] (exact fp32 values, L2-hot)
    for (int i = tid; i < ROWS_BLK * 32; i += 256) {
        int r = i >> 5, q = i & 31;
        int code = sidx[r];
        float4 v = *(const float4*)(embed + (size_t)code * D + q * 4);
        *(float4*)(out_q + (rowblk + r) * (long)D + q * 4) = v;
    }
}

// ---------------- recheck: exact fp32 rescore of flagged rows ----------------
__global__ __launch_bounds__(256)
void ecb_recheck(const float* __restrict__ x, const float* __restrict__ embed,
                 const float* __restrict__ csq,
                 float* __restrict__ out_idx, float* __restrict__ out_q,
                 const unsigned int* __restrict__ counter,
                 const unsigned int* __restrict__ list, int N) {
    __shared__ float xs[D];
    __shared__ float bv[256];
    __shared__ int   bi[256];
    const int tid = threadIdx.x;
    unsigned cnt = *counter;
    if (cnt > (unsigned)N) cnt = (unsigned)N;

    for (unsigned it = blockIdx.x; it < cnt; it += gridDim.x) {
        const long row = (long)list[it];
        if (tid < 32) *(float4*)&xs[tid * 4] = *(const float4*)(x + row * D + tid * 4);
        __syncthreads();

        float best = -INFINITY; int bidx = 0;
#pragma unroll
        for (int g = 0; g < 4; ++g) {
            int code = tid + g * 256;
            const float* er = embed + (size_t)code * D;
            float dot = 0.f;
#pragma unroll
            for (int k = 0; k < 32; ++k) {
                float4 e = *(const float4*)(er + k * 4);
                dot = fmaf(xs[k * 4 + 0], e.x, dot);
                dot = fmaf(xs[k * 4 + 1], e.y, dot);
                dot = fmaf(xs[k * 4 + 2], e.z, dot);
                dot = fmaf(xs[k * 4 + 3], e.w, dot);
            }
            float sc = fmaf(2.f, dot, -csq[code]);
            if (sc > best || (sc == best && code < bidx)) { best = sc; bidx = code; }
        }
        bv[tid] = best; bi[tid] = bidx;
        __syncthreads();
        for (int s = 128; s > 0; s >>= 1) {
            if (tid < s) {
                float ov = bv[tid + s]; int oi = bi[tid + s];
                if (ov > bv[tid] || (ov == bv[tid] && oi < bi[tid])) { bv[tid] = ov; bi[tid] = oi; }
            }
            __syncthreads();
        }
        const int win = bi[0];
        if (tid == 0) out_idx[row] = (float)win;
        if (tid < 32) {
            float4 v = *(const float4*)(embed + (size_t)win * D + tid * 4);
            *(float4*)(out_q + row * D + tid * 4) = v;
        }
        __syncthreads();
    }
}

extern "C" void kernel_launch(void* const* d_in, const int* in_sizes, int n_in,
                              void* d_out, int out_size, void* d_ws, size_t ws_size,
                              hipStream_t stream) {
    const float* x     = (const float*)d_in[0];
    const float* embed = (const float*)d_in[1];
    const int N = in_sizes[0] / D;   // 131072
    char* ws = (char*)d_ws;
    unsigned int*   counter = (unsigned int*)(ws + WS_COUNTER);
    float*          csq     = (float*)(ws + WS_CSQ);
    unsigned short* ehi     = (unsigned short*)(ws + WS_EHI);
    unsigned short* elo     = (unsigned short*)(ws + WS_ELO);
    unsigned int*   list    = (unsigned int*)(ws + WS_LIST);
    float* out_idx = (float*)d_out;
    float* out_q   = out_idx + N;

    hipLaunchKernelGGL(ecb_prep, dim3(16), dim3(64), 0, stream, embed, csq, ehi, elo, counter);
    hipLaunchKernelGGL(ecb_main, dim3(N / ROWS_BLK), dim3(256), 0, stream,
                       x, ehi, elo, csq, embed, out_idx, out_q, counter, list);
    hipLaunchKernelGGL(ecb_recheck, dim3(512), dim3(256), 0, stream,
                       x, embed, csq, out_idx, out_q, counter, list, N);
}

// Round 5
// 231.401 us; speedup vs baseline: 23.8451x; 1.0796x over previous
//
#include <hip/hip_runtime.h>
#include <math.h>

// EuclideanCodebook: N=131072 rows x d=128 fp32, K=1024 codes.
// bf16x3 split-precision MFMA (xh*eh + xl*eh + xh*el), per-row top-2 gap
// tracking, exact fp32 recheck of rows with gap < TAU.
// R2: 64 rows/wave spilled A-frags -> 1.07 GB scratch traffic. Fixed: 32 rows.
// R3: partial unroll made ah[s] dynamically-indexed -> cndmask waterfall.
//     Fixed: full s-unroll, t-loop unroll 1.
// R5: (a) 2 independent MFMA accumulation chains (was one 24-deep chain),
//     (b) 3 blocks/CU (launch_bounds(256,3), scsq LDS staging dropped),
//     (c) recheck reads a transposed codebook -> coalesced (was 64 lines/instr).

typedef __attribute__((ext_vector_type(8)))  short short8_t;   // 8 bf16
typedef __attribute__((ext_vector_type(16))) float floatx16;   // 32x32 C frag

constexpr int D        = 128;
constexpr int KCODES   = 1024;
constexpr int NTILES   = 32;      // 1024 / 32 codes-per-tile
constexpr int ROWS_BLK = 128;     // 4 waves x 32 rows
constexpr float TAU    = 0.015f;  // recheck margin >> 5-sigma score error (~2e-3)
constexpr unsigned LIST_CAP = 65536;

// ws layout (bytes); total ~1.26 MB
constexpr size_t WS_COUNTER = 0;
constexpr size_t WS_CSQ     = 256;                   // 1024 f32
constexpr size_t WS_EHI     = 8192;                  // 1024*128 ushort, swizzled
constexpr size_t WS_ELO     = WS_EHI + 262144;
constexpr size_t WS_LIST    = WS_ELO + 262144;       // 65536 uint
constexpr size_t WS_EMBT    = WS_LIST + 262144;      // 128*1024 f32 transposed

#define GLOBAL_AS __attribute__((address_space(1)))
#define LDS_AS    __attribute__((address_space(3)))

__device__ inline unsigned short bf16_rne(float v, float* back) {
    unsigned u = __float_as_uint(v);
    unsigned r = (u + 0x7FFFu + ((u >> 16) & 1u)) >> 16;
    *back = __uint_as_float(r << 16);
    return (unsigned short)r;
}

// ------- prep: csq + swizzled bf16 hi/lo codebook + transposed codebook -------
__global__ void ecb_prep(const float* __restrict__ embed, float* __restrict__ csq,
                         unsigned short* __restrict__ ehi, unsigned short* __restrict__ elo,
                         float* __restrict__ embT, unsigned int* __restrict__ counter) {
    int n = blockIdx.x * 64 + threadIdx.x;
    if (n == 0) *counter = 0u;
    if (n >= KCODES) return;
    const int t = n >> 5, nn = n & 31, nm = nn & 15;
    const float* row = embed + (size_t)n * D;
    const size_t tb = (size_t)t * 32 * D + (size_t)nn * D;
    float s = 0.f;
#pragma unroll
    for (int cc = 0; cc < 16; ++cc) {
        float4 a  = *(const float4*)(row + cc * 8);
        float4 bq = *(const float4*)(row + cc * 8 + 4);
        s = fmaf(a.x, a.x, s);  s = fmaf(a.y, a.y, s);
        s = fmaf(a.z, a.z, s);  s = fmaf(a.w, a.w, s);
        s = fmaf(bq.x, bq.x, s); s = fmaf(bq.y, bq.y, s);
        s = fmaf(bq.z, bq.z, s); s = fmaf(bq.w, bq.w, s);
        float vv[8] = {a.x, a.y, a.z, a.w, bq.x, bq.y, bq.z, bq.w};
#pragma unroll
        for (int j = 0; j < 8; ++j) embT[(size_t)(cc * 8 + j) * KCODES + n] = vv[j];
        unsigned short h[8], l[8];
#pragma unroll
        for (int j = 0; j < 8; ++j) {
            float hb, db;
            h[j] = bf16_rne(vv[j], &hb);
            l[j] = bf16_rne(vv[j] - hb, &db);
        }
        uint4 ph, pl;
        ph.x = (unsigned)h[0] | ((unsigned)h[1] << 16);
        ph.y = (unsigned)h[2] | ((unsigned)h[3] << 16);
        ph.z = (unsigned)h[4] | ((unsigned)h[5] << 16);
        ph.w = (unsigned)h[6] | ((unsigned)h[7] << 16);
        pl.x = (unsigned)l[0] | ((unsigned)l[1] << 16);
        pl.y = (unsigned)l[2] | ((unsigned)l[3] << 16);
        pl.z = (unsigned)l[4] | ((unsigned)l[5] << 16);
        pl.w = (unsigned)l[6] | ((unsigned)l[7] << 16);
        // XOR swizzle on the 16B chunk index -> conflict-free ds_read_b128 later
        size_t dst = tb + (size_t)((cc ^ nm) * 8);
        *(uint4*)(ehi + dst) = ph;
        *(uint4*)(elo + dst) = pl;
    }
    csq[n] = s;
}

// ---------------- main: MFMA scores + stuffed-index argmax ----------------
__global__ __launch_bounds__(256, 3)
void ecb_main(const float* __restrict__ x,
              const unsigned short* __restrict__ ehi, const unsigned short* __restrict__ elo,
              const float* __restrict__ csq, const float* __restrict__ embed,
              float* __restrict__ out_idx, float* __restrict__ out_q,
              unsigned int* __restrict__ counter, unsigned int* __restrict__ list) {
    __shared__ unsigned short ebuf[2][2][4096];   // [dbuf][hi/lo][32 codes x 128], 32 KB
    __shared__ int sidx[ROWS_BLK];                // 512 B

    const int tid  = threadIdx.x;
    const int lane = tid & 63, wave = tid >> 6;
    const int col  = lane & 31, h = lane >> 5, colm = col & 15;
    const long rowblk = (long)blockIdx.x * ROWS_BLK;
    const int  roww   = wave * 32;

    // A prologue: 32 rows/wave of x -> bf16 hi/lo fragments in registers.
    short8_t ah[8], al[8];
    {
        const float* xr = x + (rowblk + roww + col) * (long)D + h * 8;
#pragma unroll
        for (int c = 0; c < 8; ++c) {
            float4 a  = *(const float4*)(xr + c * 16);
            float4 bq = *(const float4*)(xr + c * 16 + 4);
            float vv[8] = {a.x, a.y, a.z, a.w, bq.x, bq.y, bq.z, bq.w};
            short8_t fh, fl;
#pragma unroll
            for (int j = 0; j < 8; ++j) {
                float hb, db;
                fh[j] = (short)bf16_rne(vv[j], &hb);
                fl[j] = (short)bf16_rne(vv[j] - hb, &db);
            }
            ah[c] = fh;
            al[c] = fl;
        }
    }

    auto stage = [&](int t, int b) {
        const char* gh = (const char*)(ehi) + (size_t)t * 8192;
        const char* gl = (const char*)(elo) + (size_t)t * 8192;
        char* lh = (char*)&ebuf[b][0][0];
        char* ll = (char*)&ebuf[b][1][0];
#pragma unroll
        for (int i = 0; i < 2; ++i) {
            int off = i * 4096 + wave * 1024;
            __builtin_amdgcn_global_load_lds((const GLOBAL_AS unsigned int*)(gh + off + lane * 16),
                                             (LDS_AS unsigned int*)(lh + off), 16, 0, 0);
            __builtin_amdgcn_global_load_lds((const GLOBAL_AS unsigned int*)(gl + off + lane * 16),
                                             (LDS_AS unsigned int*)(ll + off), 16, 0, 0);
        }
    };

    float v1[16], v2[16];
#pragma unroll
    for (int j = 0; j < 16; ++j) { v1[j] = -INFINITY; v2[j] = -INFINITY; }

    stage(0, 0);
    __syncthreads();

#pragma unroll 1
    for (int t = 0; t < NTILES; ++t) {
        const int b = t & 1;
        if (t + 1 < NTILES) stage(t + 1, (t + 1) & 1);

        const float cs = csq[t * 32 + col];   // L1-hot 4 KB table

        floatx16 accA, accB;   // 2 independent chains (was one 24-deep chain)
#pragma unroll
        for (int i = 0; i < 16; ++i) { accA[i] = 0.f; accB[i] = 0.f; }

        // FULL unroll: constant indices keep ah[s]/al[s] in registers (R3 bug).
#pragma unroll
        for (int s = 0; s < 8; ++s) {
            const int cc = 2 * s + h;
            const int idx = (col * 16 + (cc ^ colm)) * 8;   // elements
            short8_t bh = *(const short8_t*)&ebuf[b][0][idx];
            short8_t bl = *(const short8_t*)&ebuf[b][1][idx];
            accA = __builtin_amdgcn_mfma_f32_32x32x16_bf16(ah[s], bh, accA, 0, 0, 0);
            accB = __builtin_amdgcn_mfma_f32_32x32x16_bf16(al[s], bh, accB, 0, 0, 0);
            accB = __builtin_amdgcn_mfma_f32_32x32x16_bf16(ah[s], bl, accB, 0, 0, 0);
        }

        // epilogue: score = 2*(accA+accB) - ||e||^2 ; tile id in mantissa LSBs
#pragma unroll
        for (int j = 0; j < 16; ++j) {
            float sc = fmaf(2.f, accA[j] + accB[j], -cs);
            unsigned u = (__float_as_uint(sc) & ~31u) | (unsigned)t;
            float cand = __uint_as_float(u);
            float mn = fminf(v1[j], cand);
            v1[j] = fmaxf(v1[j], cand);
            v2[j] = fmaxf(v2[j], mn);
        }
        __syncthreads();
    }

    // cross-lane top-2 merge over the 32 columns of each half
#pragma unroll
    for (int j = 0; j < 16; ++j) {
        float a1 = v1[j], a2 = v2[j];
        int   c1 = ((__float_as_uint(a1) & 31u) << 5) | col;   // tile*32 + col
#pragma unroll
        for (int m = 1; m < 32; m <<= 1) {
            float o1 = __shfl_xor(a1, m, 64);
            int   oc = __shfl_xor(c1, m, 64);
            float o2 = __shfl_xor(a2, m, 64);
            float lo = fminf(a1, o1);
            if (o1 > a1) { a1 = o1; c1 = oc; }
            a2 = fmaxf(fmaxf(a2, o2), lo);
        }
        if (col == j) {
            int row_local = roww + (j & 3) + 8 * (j >> 2) + 4 * h;
            long grow = rowblk + row_local;
            sidx[row_local] = c1;
            out_idx[grow] = (float)c1;
            if (a1 - a2 < TAU) {
                unsigned p = atomicAdd(counter, 1u);
                if (p < LIST_CAP) list[p] = (unsigned)grow;
            }
        }
    }
    __syncthreads();

    // gather quantize = embed[best] (exact fp32 values, L2-hot)
    for (int i = tid; i < ROWS_BLK * 32; i += 256) {
        int r = i >> 5, q = i & 31;
        int code = sidx[r];
        float4 v = *(const float4*)(embed + (size_t)code * D + q * 4);
        *(float4*)(out_q + (rowblk + r) * (long)D + q * 4) = v;
    }
}

// ------- recheck: exact fp32 rescore of flagged rows (coalesced embT) -------
__global__ __launch_bounds__(256)
void ecb_recheck(const float* __restrict__ x, const float* __restrict__ embT,
                 const float* __restrict__ embed, const float* __restrict__ csq,
                 float* __restrict__ out_idx, float* __restrict__ out_q,
                 const unsigned int* __restrict__ counter,
                 const unsigned int* __restrict__ list) {
    __shared__ float xs[D];
    __shared__ float bv[256];
    __shared__ int   bi[256];
    const int tid = threadIdx.x;
    unsigned cnt = *counter;
    if (cnt > LIST_CAP) cnt = LIST_CAP;
    const float4* eT = (const float4*)embT;   // [k][256 x float4-of-codes]

    for (unsigned it = blockIdx.x; it < cnt; it += gridDim.x) {
        const long row = (long)list[it];
        if (tid < 32) *(float4*)&xs[tid * 4] = *(const float4*)(x + row * D + tid * 4);
        __syncthreads();

        // 4 consecutive codes per thread; k-sequential fp32 order (matches R4)
        float4 dot = {0.f, 0.f, 0.f, 0.f};
        for (int k = 0; k < D; ++k) {
            float xv = xs[k];
            float4 e = eT[(size_t)k * 256 + tid];
            dot.x = fmaf(xv, e.x, dot.x);
            dot.y = fmaf(xv, e.y, dot.y);
            dot.z = fmaf(xv, e.z, dot.z);
            dot.w = fmaf(xv, e.w, dot.w);
        }
        const int c0 = tid * 4;
        float best = -INFINITY; int bidx = 0;
        float scs[4] = {fmaf(2.f, dot.x, -csq[c0]),
                        fmaf(2.f, dot.y, -csq[c0 + 1]),
                        fmaf(2.f, dot.z, -csq[c0 + 2]),
                        fmaf(2.f, dot.w, -csq[c0 + 3])};
#pragma unroll
        for (int i = 0; i < 4; ++i)
            if (scs[i] > best) { best = scs[i]; bidx = c0 + i; }
        bv[tid] = best; bi[tid] = bidx;
        __syncthreads();
        for (int s = 128; s > 0; s >>= 1) {
            if (tid < s) {
                float ov = bv[tid + s]; int oi = bi[tid + s];
                if (ov > bv[tid] || (ov == bv[tid] && oi < bi[tid])) { bv[tid] = ov; bi[tid] = oi; }
            }
            __syncthreads();
        }
        const int win = bi[0];
        if (tid == 0) out_idx[row] = (float)win;
        if (tid < 32) {
            float4 v = *(const float4*)(embed + (size_t)win * D + tid * 4);
            *(float4*)(out_q + row * D + tid * 4) = v;
        }
        __syncthreads();
    }
}

extern "C" void kernel_launch(void* const* d_in, const int* in_sizes, int n_in,
                              void* d_out, int out_size, void* d_ws, size_t ws_size,
                              hipStream_t stream) {
    const float* x     = (const float*)d_in[0];
    const float* embed = (const float*)d_in[1];
    const int N = in_sizes[0] / D;   // 131072
    char* ws = (char*)d_ws;
    unsigned int*   counter = (unsigned int*)(ws + WS_COUNTER);
    float*          csq     = (float*)(ws + WS_CSQ);
    unsigned short* ehi     = (unsigned short*)(ws + WS_EHI);
    unsigned short* elo     = (unsigned short*)(ws + WS_ELO);
    unsigned int*   list    = (unsigned int*)(ws + WS_LIST);
    float*          embT    = (float*)(ws + WS_EMBT);
    float* out_idx = (float*)d_out;
    float* out_q   = out_idx + N;

    hipLaunchKernelGGL(ecb_prep, dim3(16), dim3(64), 0, stream,
                       embed, csq, ehi, elo, embT, counter);
    hipLaunchKernelGGL(ecb_main, dim3(N / ROWS_BLK), dim3(256), 0, stream,
                       x, ehi, elo, csq, embed, out_idx, out_q, counter, list);
    hipLaunchKernelGGL(ecb_recheck, dim3(1024), dim3(256), 0, stream,
                       x, embT, embed, csq, out_idx, out_q, counter, list);
}